// Round 6
// baseline (169.660 us; speedup 1.0000x reference)
//
#include <hip/hip_runtime.h>
#include <hip/hip_bf16.h>

#define B_ROWS 4096
#define DIN    768
#define DOUT   512
#define QDIM   64
#define H1C    32
#define H2C    64

typedef float f32x4_t __attribute__((ext_vector_type(4)));

__device__ __forceinline__ float bf16bits_to_f32(unsigned short u) {
  return __builtin_bit_cast(float, ((unsigned int)u) << 16);
}
// dual-dtype scalar load: isb -> buffer holds bf16, else fp32
__device__ __forceinline__ float ldf(const void* p, int i, bool isb) {
  if (isb) return bf16bits_to_f32(((const unsigned short*)p)[i]);
  return ((const float*)p)[i];
}

// ---------- kernel 0: dtype detector (verified: picks fp32 on this harness) ----------
__global__ __launch_bounds__(256) void k_detect(const unsigned int* __restrict__ xw,
                                                int* __restrict__ flag)
{
  const int t = threadIdx.x;
  int hit = 0;
  for (int i = t; i < 4096; i += 256) {
    const unsigned int e = (xw[i] >> 7) & 0xffu;
    if (e >= 118u && e <= 127u) hit++;
  }
#pragma unroll
  for (int off = 32; off >= 1; off >>= 1) hit += __shfl_down(hit, off);
  __shared__ int red[4];
  if ((t & 63) == 0) red[t >> 6] = hit;
  __syncthreads();
  if (t == 0) {
    const int total = red[0] + red[1] + red[2] + red[3];
    *flag = (total >= 2048) ? 1 : 0;   // 1 = buffers are bf16
  }
}

// ---------- kernel 1: x_proj = x @ wp + bp, pure fp32 VALU SGEMM ----------
// 64x64 tile, BK=16, 256 threads as 16x16, each computing a 4x4 micro-tile.
// Deliberately NO MFMA / NO bf16: removes every layout assumption under test.
__global__ __launch_bounds__(256) void k_gemm_valu(
    const void* __restrict__ x,      // [4096][768]
    const void* __restrict__ wp,     // [768][512]
    const void* __restrict__ bp,     // [512]
    float* __restrict__ xp,          // [4096][512] fp32 (in d_ws)
    const int* __restrict__ flag)
{
  __shared__ alignas(16) float As[16][64];   // [k][m]
  __shared__ alignas(16) float Bs[16][64];   // [k][n]

  const bool isb = (*flag != 0);
  const int t  = threadIdx.x;
  const int m0 = blockIdx.y * 64, n0 = blockIdx.x * 64;
  const int tx = t & 15, ty = t >> 4;          // 16x16 thread grid
  const int ar = t >> 2,  akk = (t & 3) * 4;   // A staging: row ar, k akk..+3
  const int bkr = t >> 4, bc  = (t & 15) * 4;  // B staging: k-row bkr, col bc..+3

  float acc[4][4] = {};

  for (int k0 = 0; k0 < DIN; k0 += 16) {
    float a4[4], b4[4];
    if (isb) {
      const unsigned short* xa = (const unsigned short*)x + (size_t)(m0 + ar) * DIN + k0 + akk;
#pragma unroll
      for (int j = 0; j < 4; ++j) a4[j] = bf16bits_to_f32(xa[j]);
      const unsigned short* wb = (const unsigned short*)wp + (size_t)(k0 + bkr) * DOUT + n0 + bc;
#pragma unroll
      for (int j = 0; j < 4; ++j) b4[j] = bf16bits_to_f32(wb[j]);
    } else {
      const float4 fa = *(const float4*)((const float*)x + (size_t)(m0 + ar) * DIN + k0 + akk);
      a4[0] = fa.x; a4[1] = fa.y; a4[2] = fa.z; a4[3] = fa.w;
      const float4 fb = *(const float4*)((const float*)wp + (size_t)(k0 + bkr) * DOUT + n0 + bc);
      b4[0] = fb.x; b4[1] = fb.y; b4[2] = fb.z; b4[3] = fb.w;
    }

    __syncthreads();   // previous tile's LDS reads complete
#pragma unroll
    for (int j = 0; j < 4; ++j) As[akk + j][ar] = a4[j];   // transpose-scatter
#pragma unroll
    for (int j = 0; j < 4; ++j) Bs[bkr][bc + j] = b4[j];
    __syncthreads();   // stores visible

#pragma unroll
    for (int kk = 0; kk < 16; ++kk) {
      const float4 av = *(const float4*)&As[kk][ty * 4];
      const float4 bv = *(const float4*)&Bs[kk][tx * 4];
      const float aa[4] = {av.x, av.y, av.z, av.w};
      const float bb[4] = {bv.x, bv.y, bv.z, bv.w};
#pragma unroll
      for (int i = 0; i < 4; ++i)
#pragma unroll
        for (int j = 0; j < 4; ++j)
          acc[i][j] = fmaf(aa[i], bb[j], acc[i][j]);
    }
  }

  // epilogue: unambiguous indexing — thread (ty,tx) owns rows ty*4+i, cols tx*4+j
#pragma unroll
  for (int i = 0; i < 4; ++i) {
    const int grow = m0 + ty * 4 + i;
    float4 o;
    o.x = acc[i][0] + ldf(bp, n0 + tx * 4 + 0, isb);
    o.y = acc[i][1] + ldf(bp, n0 + tx * 4 + 1, isb);
    o.z = acc[i][2] + ldf(bp, n0 + tx * 4 + 2, isb);
    o.w = acc[i][3] + ldf(bp, n0 + tx * 4 + 3, isb);
    *(float4*)&xp[(size_t)grow * DOUT + n0 + tx * 4] = o;
  }
}

// ---------- kernel 2: S -> u -> T -> summed -> LayerNorm, 8 rows/block ----------
// UNCHANGED structure from round 5 (control variable), xp now fp32.
__global__ __launch_bounds__(256) void k_tail(
    const float* __restrict__ xp,    // fp32, in d_ws
    const void* __restrict__ wi1, const void* __restrict__ bi1,
    const void* __restrict__ wi2, const void* __restrict__ bi2,
    const void* __restrict__ wo1, const void* __restrict__ bo1,
    const void* __restrict__ wo2, const void* __restrict__ bo2,
    const void* __restrict__ gamma, const void* __restrict__ beta,
    float* __restrict__ out,
    const int* __restrict__ flag)
{
  __shared__ alignas(16) float sXp[8 * 512];
  __shared__ float sWi2[H1C * QDIM];
  __shared__ float sS[8 * H1C];
  __shared__ float sU[8 * QDIM];
  __shared__ float sT[8 * H2C];
  __shared__ float sW1[H1C], sB1[H1C], sBi2[QDIM], sWo1[H2C], sBo1[H2C];
  __shared__ float sRed[4][8][2];
  __shared__ float sStats[8][2];

  const bool isb = (*flag != 0);
  const int t  = threadIdx.x;
  const int b0 = blockIdx.x * 8;

  const float* xpb = xp + (size_t)b0 * DOUT;
  for (int i = t * 4; i < 8 * 512; i += 256 * 4)
    *(float4*)&sXp[i] = *(const float4*)&xpb[i];
  for (int i = t; i < H1C * QDIM; i += 256) sWi2[i] = ldf(wi2, i, isb);
  if (t < 32)                   { sW1[t] = ldf(wi1, t, isb); sB1[t] = ldf(bi1, t, isb); }
  else if (t >= 64 && t < 128)  { const int j = t - 64;  sBi2[j] = ldf(bi2, j, isb); }
  else if (t >= 128 && t < 192) { const int j = t - 128; sWo1[j] = ldf(wo1, j, isb); }
  else if (t >= 192)            { const int j = t - 192; sBo1[j] = ldf(bo1, j, isb); }
  __syncthreads();

  // Phase S: S[r][h] = sum_d relu(xp[r][d]*wi1[h] + bi1[h])
  {
    const int h = t & 31, r = t >> 5;
    const float w = sW1[h], bb = sB1[h];
    const float* row = &sXp[r * 512];
    float acc = 0.f;
    for (int d = 0; d < 512; d += 4) {
      const float4 v = *(const float4*)&row[d];
      acc += fmaxf(fmaf(v.x, w, bb), 0.f);
      acc += fmaxf(fmaf(v.y, w, bb), 0.f);
      acc += fmaxf(fmaf(v.z, w, bb), 0.f);
      acc += fmaxf(fmaf(v.w, w, bb), 0.f);
    }
    sS[r * H1C + h] = acc;
  }
  __syncthreads();

  // Phase u: u[r][q] = sum_h S[r][h]*wi2[h][q] + 512*bi2[q]
  for (int e = t; e < 8 * QDIM; e += 256) {
    const int r = e >> 6, q = e & 63;
    float acc = 0.f;
#pragma unroll
    for (int h = 0; h < H1C; ++h) acc = fmaf(sS[r * H1C + h], sWi2[h * QDIM + q], acc);
    sU[e] = acc + 512.f * sBi2[q];
  }
  __syncthreads();

  // Phase T: T[r][g] = sum_q relu(u[r][q]*wo1[g] + bo1[g])
  for (int e = t; e < 8 * H2C; e += 256) {
    const int r = e >> 6, g = e & 63;
    const float w = sWo1[g], bb = sBo1[g];
    float acc = 0.f;
#pragma unroll
    for (int q = 0; q < QDIM; ++q) acc += fmaxf(fmaf(sU[r * QDIM + q], w, bb), 0.f);
    sT[e] = acc;
  }
  __syncthreads();

  // Phase summed + LN: thread t owns columns d0=2t, d0+1 for all 8 rows
  const int d0 = 2 * t;
  float a0[8], a1[8];
#pragma unroll
  for (int r = 0; r < 8; ++r) { a0[r] = 0.f; a1[r] = 0.f; }

  for (int g = 0; g < H2C; ++g) {
    float w0, w1;
    if (isb) {
      const unsigned int pk = *(const unsigned int*)((const unsigned short*)wo2 + g * DOUT + d0);
      w0 = bf16bits_to_f32((unsigned short)(pk & 0xffffu));
      w1 = __builtin_bit_cast(float, pk & 0xffff0000u);
    } else {
      const float2 f = *(const float2*)((const float*)wo2 + g * DOUT + d0);
      w0 = f.x; w1 = f.y;
    }
#pragma unroll
    for (int r = 0; r < 8; ++r) {
      const float tv = sT[r * H2C + g];
      a0[r] = fmaf(tv, w0, a0[r]);
      a1[r] = fmaf(tv, w1, a1[r]);
    }
  }
  const float bb0 = 64.f * ldf(bo2, d0, isb);
  const float bb1 = 64.f * ldf(bo2, d0 + 1, isb);
#pragma unroll
  for (int r = 0; r < 8; ++r) { a0[r] += bb0; a1[r] += bb1; }

  float pr[8], prs[8];
#pragma unroll
  for (int r = 0; r < 8; ++r) {
    pr[r]  = a0[r] + a1[r];
    prs[r] = a0[r] * a0[r] + a1[r] * a1[r];
  }
#pragma unroll
  for (int off = 1; off < 64; off <<= 1) {
#pragma unroll
    for (int r = 0; r < 8; ++r) {
      pr[r]  += __shfl_xor(pr[r],  off);
      prs[r] += __shfl_xor(prs[r], off);
    }
  }
  const int wv = t >> 6, ln = t & 63;
  if (ln == 0) {
#pragma unroll
    for (int r = 0; r < 8; ++r) { sRed[wv][r][0] = pr[r]; sRed[wv][r][1] = prs[r]; }
  }
  __syncthreads();
  if (t < 8) {
    const float sm = sRed[0][t][0] + sRed[1][t][0] + sRed[2][t][0] + sRed[3][t][0];
    const float sq = sRed[0][t][1] + sRed[1][t][1] + sRed[2][t][1] + sRed[3][t][1];
    const float mu  = sm * (1.f / 512.f);
    const float var = fmaxf(sq * (1.f / 512.f) - mu * mu, 0.f);
    sStats[t][0] = mu;
    sStats[t][1] = rsqrtf(var + 1e-5f);
  }
  __syncthreads();

  const float g0 = ldf(gamma, d0, isb),  g1 = ldf(gamma, d0 + 1, isb);
  const float be0 = ldf(beta, d0, isb),  be1 = ldf(beta, d0 + 1, isb);
#pragma unroll
  for (int r = 0; r < 8; ++r) {
    const float mu = sStats[r][0], rstd = sStats[r][1];
    float* op = out + (size_t)(b0 + r) * DOUT + d0;
    op[0] = (a0[r] - mu) * rstd * g0 + be0;
    op[1] = (a1[r] - mu) * rstd * g1 + be1;
  }
}

extern "C" void kernel_launch(void* const* d_in, const int* in_sizes, int n_in,
                              void* d_out, int out_size, void* d_ws, size_t ws_size,
                              hipStream_t stream) {
  const void* x     = d_in[0];
  const void* wp    = d_in[1];
  const void* bp    = d_in[2];
  const void* wi1   = d_in[3];
  const void* bi1   = d_in[4];
  const void* wi2   = d_in[5];
  const void* bi2   = d_in[6];
  const void* wo1   = d_in[7];
  const void* bo1   = d_in[8];
  const void* wo2   = d_in[9];
  const void* bo2   = d_in[10];
  const void* gamma = d_in[11];
  const void* beta  = d_in[12];

  int* flag = (int*)d_ws;                               // 4 B
  float* xp = (float*)((char*)d_ws + 4096);             // 8 MB fp32
  // ws usage ~8 MB; R3 demonstrated >= 11 MB is available.

  k_detect<<<1, 256, 0, stream>>>((const unsigned int*)x, flag);
  k_gemm_valu<<<dim3(DOUT / 64, B_ROWS / 64), 256, 0, stream>>>(x, wp, bp, xp, flag);
  k_tail<<<B_ROWS / 8, 256, 0, stream>>>(xp, wi1, bi1, wi2, bi2, wo1, bo1,
                                         wo2, bo2, gamma, beta,
                                         (float*)d_out, flag);
}

// Round 7
// 141.329 us; speedup vs baseline: 1.2005x; 1.2005x over previous
//
#include <hip/hip_runtime.h>
#include <hip/hip_bf16.h>

#define B_ROWS 4096
#define DIN    768
#define DOUT   512
#define QDIM   64
#define H1C    32
#define H2C    64

typedef short  short8_t  __attribute__((ext_vector_type(8)));
typedef __bf16 bf16x8_t  __attribute__((ext_vector_type(8)));
typedef float  f32x4_t   __attribute__((ext_vector_type(4)));

__device__ __forceinline__ float bf16bits_to_f32(unsigned short u) {
  return __builtin_bit_cast(float, ((unsigned int)u) << 16);
}
__device__ __forceinline__ unsigned short f32_to_bf16bits(float f) {
  return __builtin_bit_cast(unsigned short, __float2bfloat16(f));
}
// dual-dtype scalar load: isb -> buffer holds bf16, else fp32
__device__ __forceinline__ float ldf(const void* p, int i, bool isb) {
  if (isb) return bf16bits_to_f32(((const unsigned short*)p)[i]);
  return ((const float*)p)[i];
}

// ---------- kernel 0: dtype detector (verified: picks fp32 on this harness) ----------
__global__ __launch_bounds__(256) void k_detect(const unsigned int* __restrict__ xw,
                                                int* __restrict__ flag)
{
  const int t = threadIdx.x;
  int hit = 0;
  for (int i = t; i < 4096; i += 256) {
    const unsigned int e = (xw[i] >> 7) & 0xffu;
    if (e >= 118u && e <= 127u) hit++;
  }
#pragma unroll
  for (int off = 32; off >= 1; off >>= 1) hit += __shfl_down(hit, off);
  __shared__ int red[4];
  if ((t & 63) == 0) red[t >> 6] = hit;
  __syncthreads();
  if (t == 0) {
    const int total = red[0] + red[1] + red[2] + red[3];
    *flag = (total >= 2048) ? 1 : 0;   // 1 = buffers are bf16
  }
}

// ---------- kernel 1: x_proj = x @ wp + bp, bf16 MFMA, fp32 out ----------
// SINGLE-VARIABLE EXPERIMENT vs round 6: only this kernel changed (VALU->MFMA);
// tail is byte-identical, xp stays fp32. Grid axis swap: m=blockIdx.x so the
// 8 n-blocks sharing x rows get linear IDs = m (mod 8) -> same XCD -> x fetched
// from HBM once (round-6 FETCH was 50 MB vs ~14 MB ideal).
__global__ __launch_bounds__(256) void k_gemm_mfma(
    const void* __restrict__ x,      // [4096][768]
    const void* __restrict__ wp,     // [768][512]
    const void* __restrict__ bp,     // [512]
    float* __restrict__ xp,          // [4096][512] fp32 (in d_ws)
    const int* __restrict__ flag)
{
  __shared__ alignas(16) unsigned short As[64 * 32];   // [m][k]
  __shared__ alignas(16) unsigned short Bs[64 * 32];   // [n][k]

  const bool isb = (*flag != 0);
  const int tid  = threadIdx.x;
  const int wave = tid >> 6;
  const int lane = tid & 63;
  const int m0 = blockIdx.x * 64;   // swapped: m on x-dim (XCD co-location)
  const int n0 = blockIdx.y * 64;

  const int sr = tid >> 2, ak = (tid & 3) * 8;   // A: row sr, k-chunk ak
  const int bn = tid & 63, bk = (tid >> 6) * 8;  // B: col bn, k-chunk bk

  const int wm = wave >> 1, wn = wave & 1;
  const int mrow = wm * 32, ncol = wn * 32;
  const int lm = lane & 15, quad = lane >> 4;

  f32x4_t acc[2][2] = {};

  for (int kt = 0; kt < DIN / 32; ++kt) {
    const int k0 = kt * 32;

    unsigned short a8[8];
    if (isb) {
      const short8_t v = *(const short8_t*)
          ((const unsigned short*)x + (size_t)(m0 + sr) * DIN + k0 + ak);
#pragma unroll
      for (int j = 0; j < 8; ++j) a8[j] = (unsigned short)v[j];
    } else {
      const float* p = (const float*)x + (size_t)(m0 + sr) * DIN + k0 + ak;
      const float4 f0 = *(const float4*)p;
      const float4 f1 = *(const float4*)(p + 4);
      a8[0] = f32_to_bf16bits(f0.x); a8[1] = f32_to_bf16bits(f0.y);
      a8[2] = f32_to_bf16bits(f0.z); a8[3] = f32_to_bf16bits(f0.w);
      a8[4] = f32_to_bf16bits(f1.x); a8[5] = f32_to_bf16bits(f1.y);
      a8[6] = f32_to_bf16bits(f1.z); a8[7] = f32_to_bf16bits(f1.w);
    }

    unsigned short b8[8];
    if (isb) {
      const unsigned short* p = (const unsigned short*)wp + (size_t)(k0 + bk) * DOUT + n0 + bn;
#pragma unroll
      for (int j = 0; j < 8; ++j) b8[j] = p[(size_t)j * DOUT];
    } else {
      const float* p = (const float*)wp + (size_t)(k0 + bk) * DOUT + n0 + bn;
#pragma unroll
      for (int j = 0; j < 8; ++j) b8[j] = f32_to_bf16bits(p[(size_t)j * DOUT]);
    }

    __syncthreads();   // previous iteration's LDS reads complete
    *(short8_t*)&As[sr * 32 + ak] = *(const short8_t*)a8;
    *(short8_t*)&Bs[bn * 32 + bk] = *(const short8_t*)b8;
    __syncthreads();   // tiles visible

#pragma unroll
    for (int mt = 0; mt < 2; ++mt) {
      const short8_t a = *(const short8_t*)&As[(mrow + mt * 16 + lm) * 32 + quad * 8];
      const bf16x8_t af = __builtin_bit_cast(bf16x8_t, a);
#pragma unroll
      for (int nt = 0; nt < 2; ++nt) {
        const short8_t b = *(const short8_t*)&Bs[(ncol + nt * 16 + lm) * 32 + quad * 8];
        const bf16x8_t bf = __builtin_bit_cast(bf16x8_t, b);
        acc[mt][nt] = __builtin_amdgcn_mfma_f32_16x16x32_bf16(af, bf, acc[mt][nt], 0, 0, 0);
      }
    }
  }

  // C/D layout: col=lane&15, row=quad*4+reg (verified m89/m91)
#pragma unroll
  for (int mt = 0; mt < 2; ++mt) {
    const int grow0 = m0 + mrow + mt * 16 + quad * 4;
#pragma unroll
    for (int nt = 0; nt < 2; ++nt) {
      const int gcol = n0 + ncol + nt * 16 + lm;
      const float bpv = ldf(bp, gcol, isb);
#pragma unroll
      for (int i = 0; i < 4; ++i)
        xp[(size_t)(grow0 + i) * DOUT + gcol] = acc[mt][nt][i] + bpv;
    }
  }
}

// ---------- kernel 2: S -> u -> T -> summed -> LayerNorm, 8 rows/block ----------
// BYTE-IDENTICAL to round 6 (verified control).
__global__ __launch_bounds__(256) void k_tail(
    const float* __restrict__ xp,    // fp32, in d_ws
    const void* __restrict__ wi1, const void* __restrict__ bi1,
    const void* __restrict__ wi2, const void* __restrict__ bi2,
    const void* __restrict__ wo1, const void* __restrict__ bo1,
    const void* __restrict__ wo2, const void* __restrict__ bo2,
    const void* __restrict__ gamma, const void* __restrict__ beta,
    float* __restrict__ out,
    const int* __restrict__ flag)
{
  __shared__ alignas(16) float sXp[8 * 512];
  __shared__ float sWi2[H1C * QDIM];
  __shared__ float sS[8 * H1C];
  __shared__ float sU[8 * QDIM];
  __shared__ float sT[8 * H2C];
  __shared__ float sW1[H1C], sB1[H1C], sBi2[QDIM], sWo1[H2C], sBo1[H2C];
  __shared__ float sRed[4][8][2];
  __shared__ float sStats[8][2];

  const bool isb = (*flag != 0);
  const int t  = threadIdx.x;
  const int b0 = blockIdx.x * 8;

  const float* xpb = xp + (size_t)b0 * DOUT;
  for (int i = t * 4; i < 8 * 512; i += 256 * 4)
    *(float4*)&sXp[i] = *(const float4*)&xpb[i];
  for (int i = t; i < H1C * QDIM; i += 256) sWi2[i] = ldf(wi2, i, isb);
  if (t < 32)                   { sW1[t] = ldf(wi1, t, isb); sB1[t] = ldf(bi1, t, isb); }
  else if (t >= 64 && t < 128)  { const int j = t - 64;  sBi2[j] = ldf(bi2, j, isb); }
  else if (t >= 128 && t < 192) { const int j = t - 128; sWo1[j] = ldf(wo1, j, isb); }
  else if (t >= 192)            { const int j = t - 192; sBo1[j] = ldf(bo1, j, isb); }
  __syncthreads();

  // Phase S: S[r][h] = sum_d relu(xp[r][d]*wi1[h] + bi1[h])
  {
    const int h = t & 31, r = t >> 5;
    const float w = sW1[h], bb = sB1[h];
    const float* row = &sXp[r * 512];
    float acc = 0.f;
    for (int d = 0; d < 512; d += 4) {
      const float4 v = *(const float4*)&row[d];
      acc += fmaxf(fmaf(v.x, w, bb), 0.f);
      acc += fmaxf(fmaf(v.y, w, bb), 0.f);
      acc += fmaxf(fmaf(v.z, w, bb), 0.f);
      acc += fmaxf(fmaf(v.w, w, bb), 0.f);
    }
    sS[r * H1C + h] = acc;
  }
  __syncthreads();

  // Phase u: u[r][q] = sum_h S[r][h]*wi2[h][q] + 512*bi2[q]
  for (int e = t; e < 8 * QDIM; e += 256) {
    const int r = e >> 6, q = e & 63;
    float acc = 0.f;
#pragma unroll
    for (int h = 0; h < H1C; ++h) acc = fmaf(sS[r * H1C + h], sWi2[h * QDIM + q], acc);
    sU[e] = acc + 512.f * sBi2[q];
  }
  __syncthreads();

  // Phase T: T[r][g] = sum_q relu(u[r][q]*wo1[g] + bo1[g])
  for (int e = t; e < 8 * H2C; e += 256) {
    const int r = e >> 6, g = e & 63;
    const float w = sWo1[g], bb = sBo1[g];
    float acc = 0.f;
#pragma unroll
    for (int q = 0; q < QDIM; ++q) acc += fmaxf(fmaf(sU[r * QDIM + q], w, bb), 0.f);
    sT[e] = acc;
  }
  __syncthreads();

  // Phase summed + LN: thread t owns columns d0=2t, d0+1 for all 8 rows
  const int d0 = 2 * t;
  float a0[8], a1[8];
#pragma unroll
  for (int r = 0; r < 8; ++r) { a0[r] = 0.f; a1[r] = 0.f; }

  for (int g = 0; g < H2C; ++g) {
    float w0, w1;
    if (isb) {
      const unsigned int pk = *(const unsigned int*)((const unsigned short*)wo2 + g * DOUT + d0);
      w0 = bf16bits_to_f32((unsigned short)(pk & 0xffffu));
      w1 = __builtin_bit_cast(float, pk & 0xffff0000u);
    } else {
      const float2 f = *(const float2*)((const float*)wo2 + g * DOUT + d0);
      w0 = f.x; w1 = f.y;
    }
#pragma unroll
    for (int r = 0; r < 8; ++r) {
      const float tv = sT[r * H2C + g];
      a0[r] = fmaf(tv, w0, a0[r]);
      a1[r] = fmaf(tv, w1, a1[r]);
    }
  }
  const float bb0 = 64.f * ldf(bo2, d0, isb);
  const float bb1 = 64.f * ldf(bo2, d0 + 1, isb);
#pragma unroll
  for (int r = 0; r < 8; ++r) { a0[r] += bb0; a1[r] += bb1; }

  float pr[8], prs[8];
#pragma unroll
  for (int r = 0; r < 8; ++r) {
    pr[r]  = a0[r] + a1[r];
    prs[r] = a0[r] * a0[r] + a1[r] * a1[r];
  }
#pragma unroll
  for (int off = 1; off < 64; off <<= 1) {
#pragma unroll
    for (int r = 0; r < 8; ++r) {
      pr[r]  += __shfl_xor(pr[r],  off);
      prs[r] += __shfl_xor(prs[r], off);
    }
  }
  const int wv = t >> 6, ln = t & 63;
  if (ln == 0) {
#pragma unroll
    for (int r = 0; r < 8; ++r) { sRed[wv][r][0] = pr[r]; sRed[wv][r][1] = prs[r]; }
  }
  __syncthreads();
  if (t < 8) {
    const float sm = sRed[0][t][0] + sRed[1][t][0] + sRed[2][t][0] + sRed[3][t][0];
    const float sq = sRed[0][t][1] + sRed[1][t][1] + sRed[2][t][1] + sRed[3][t][1];
    const float mu  = sm * (1.f / 512.f);
    const float var = fmaxf(sq * (1.f / 512.f) - mu * mu, 0.f);
    sStats[t][0] = mu;
    sStats[t][1] = rsqrtf(var + 1e-5f);
  }
  __syncthreads();

  const float g0 = ldf(gamma, d0, isb),  g1 = ldf(gamma, d0 + 1, isb);
  const float be0 = ldf(beta, d0, isb),  be1 = ldf(beta, d0 + 1, isb);
#pragma unroll
  for (int r = 0; r < 8; ++r) {
    const float mu = sStats[r][0], rstd = sStats[r][1];
    float* op = out + (size_t)(b0 + r) * DOUT + d0;
    op[0] = (a0[r] - mu) * rstd * g0 + be0;
    op[1] = (a1[r] - mu) * rstd * g1 + be1;
  }
}

extern "C" void kernel_launch(void* const* d_in, const int* in_sizes, int n_in,
                              void* d_out, int out_size, void* d_ws, size_t ws_size,
                              hipStream_t stream) {
  const void* x     = d_in[0];
  const void* wp    = d_in[1];
  const void* bp    = d_in[2];
  const void* wi1   = d_in[3];
  const void* bi1   = d_in[4];
  const void* wi2   = d_in[5];
  const void* bi2   = d_in[6];
  const void* wo1   = d_in[7];
  const void* bo1   = d_in[8];
  const void* wo2   = d_in[9];
  const void* bo2   = d_in[10];
  const void* gamma = d_in[11];
  const void* beta  = d_in[12];

  int* flag = (int*)d_ws;                               // 4 B
  float* xp = (float*)((char*)d_ws + 4096);             // 8 MB fp32

  k_detect<<<1, 256, 0, stream>>>((const unsigned int*)x, flag);
  // grid: x-dim = M blocks (64), y-dim = N blocks (8)  [XCD co-location]
  k_gemm_mfma<<<dim3(B_ROWS / 64, DOUT / 64), 256, 0, stream>>>(x, wp, bp, xp, flag);
  k_tail<<<B_ROWS / 8, 256, 0, stream>>>(xp, wi1, bi1, wi2, bi2, wo1, bo1,
                                         wo2, bo2, gamma, beta,
                                         (float*)d_out, flag);
}